// Round 1
// baseline (995.679 us; speedup 1.0000x reference)
//
#include <hip/hip_runtime.h>
#include <hip/hip_bf16.h>

#define NN 100000
#define EE 1600000
#define HH 128
#define GG 64
#define CC 32

// ---------------- init: zero counters/accumulators ----------------
__global__ void k_init(int* __restrict__ counts, int* __restrict__ cursor,
                       float* __restrict__ pooled, float* __restrict__ gcnt) {
    int i = blockIdx.x * blockDim.x + threadIdx.x;
    if (i < NN) { counts[i] = 0; cursor[i] = 0; }
    if (i < GG * HH) pooled[i] = 0.f;
    if (i < GG) gcnt[i] = 0.f;
}

// ---------------- in-degree histogram ----------------
__global__ void k_count(const int* __restrict__ dst, int* __restrict__ counts) {
    int e = blockIdx.x * blockDim.x + threadIdx.x;
    if (e < EE) atomicAdd(&counts[dst[e]], 1);
}

// ---------------- dinv = rsqrt(indeg + 1) ----------------
__global__ void k_dinv(const int* __restrict__ counts, float* __restrict__ dinv) {
    int i = blockIdx.x * blockDim.x + threadIdx.x;
    if (i < NN) dinv[i] = rsqrtf((float)counts[i] + 1.0f);
}

// ---------------- exclusive scan of counts -> row_off (single block) ----------------
__global__ __launch_bounds__(1024) void k_scan(const int* __restrict__ counts, int* __restrict__ row_off) {
    __shared__ int ssum[1024];
    int t = threadIdx.x;
    const int CH = (NN + 1023) / 1024;           // 98
    int beg = t * CH;
    int end = beg + CH; if (end > NN) end = NN;
    int s = 0;
    for (int i = beg; i < end && i < NN; i++) s += counts[i];
    ssum[t] = s;
    __syncthreads();
    // Hillis-Steele inclusive scan
    for (int off = 1; off < 1024; off <<= 1) {
        int tmp = (t >= off) ? ssum[t - off] : 0;
        __syncthreads();
        ssum[t] += tmp;
        __syncthreads();
    }
    int base = ssum[t] - s;                      // exclusive prefix for this segment
    for (int i = beg; i < end && i < NN; i++) { row_off[i] = base; base += counts[i]; }
    if (t == 0) row_off[NN] = EE;
}

// ---------------- scatter edges into CSR buckets ----------------
__global__ void k_scatter(const int* __restrict__ src, const int* __restrict__ dst,
                          const float* __restrict__ dinv, const int* __restrict__ row_off,
                          int* __restrict__ cursor, int* __restrict__ csr_src,
                          float* __restrict__ csr_norm) {
    int e = blockIdx.x * blockDim.x + threadIdx.x;
    if (e >= EE) return;
    int d = dst[e], s = src[e];
    int pos = row_off[d] + atomicAdd(&cursor[d], 1);
    csr_src[pos] = s;
    csr_norm[pos] = dinv[s] * dinv[d];
}

// ---------------- GEMM: Y[N,128] = X[N,128] @ W[128,128] (no bias) ----------------
// 32 rows / block, 256 threads: thread = (jgrp 0..31)*(rowsub 0..7), 4 rows x 4 cols each.
__global__ __launch_bounds__(256) void k_gemm(const float* __restrict__ X, const float* __restrict__ W,
                                              float* __restrict__ Y) {
    __shared__ float sW[HH * HH];     // 64 KB
    __shared__ float sX[32 * HH];     // 16 KB
    int tid = threadIdx.x;
    const float4* W4 = (const float4*)W;
    float4* sW4 = (float4*)sW;
    #pragma unroll
    for (int i = 0; i < 16; i++) sW4[tid + i * 256] = W4[tid + i * 256];   // 4096 float4
    size_t row0 = (size_t)blockIdx.x * 32;
    const float4* X4 = (const float4*)(X + row0 * HH);
    float4* sX4 = (float4*)sX;
    #pragma unroll
    for (int i = 0; i < 4; i++) sX4[tid + i * 256] = X4[tid + i * 256];    // 1024 float4
    __syncthreads();

    int j  = (tid & 31) * 4;   // col group
    int r0 = tid >> 5;         // 0..7
    float acc[4][4];
    #pragma unroll
    for (int r = 0; r < 4; r++)
        #pragma unroll
        for (int c = 0; c < 4; c++) acc[r][c] = 0.f;

    for (int k = 0; k < HH; k += 4) {
        float4 w[4];
        #pragma unroll
        for (int kk = 0; kk < 4; kk++) w[kk] = *(const float4*)&sW[(k + kk) * HH + j];
        #pragma unroll
        for (int r = 0; r < 4; r++) {
            float4 xv = *(const float4*)&sX[(r0 + r * 8) * HH + k];
            float xs[4] = {xv.x, xv.y, xv.z, xv.w};
            #pragma unroll
            for (int kk = 0; kk < 4; kk++) {
                acc[r][0] += xs[kk] * w[kk].x;
                acc[r][1] += xs[kk] * w[kk].y;
                acc[r][2] += xs[kk] * w[kk].z;
                acc[r][3] += xs[kk] * w[kk].w;
            }
        }
    }
    #pragma unroll
    for (int r = 0; r < 4; r++) {
        float4 o = make_float4(acc[r][0], acc[r][1], acc[r][2], acc[r][3]);
        *(float4*)&Y[(row0 + r0 + r * 8) * HH + j] = o;
    }
}

// ---------------- aggregation: O[n] = relu?( b + dinv[n]^2*T[n] + sum_edges norm*T[src] ) ----------------
// one wave (64 lanes) per node, float2 per lane.
__global__ __launch_bounds__(256) void k_agg(const float* __restrict__ T, float* __restrict__ O,
                                             const int* __restrict__ row_off, const int* __restrict__ csr_src,
                                             const float* __restrict__ csr_norm, const float* __restrict__ dinv,
                                             const float* __restrict__ bias, int relu) {
    int gt = blockIdx.x * blockDim.x + threadIdx.x;
    int n = gt >> 6;
    int lane = threadIdx.x & 63;
    if (n >= NN) return;
    int beg = row_off[n], end = row_off[n + 1];
    const float2* T2 = (const float2*)T;
    float2 acc = make_float2(0.f, 0.f);
    for (int p = beg; p < end; p++) {
        int s = csr_src[p];
        float nm = csr_norm[p];
        float2 v = T2[(size_t)s * 64 + lane];
        acc.x += nm * v.x;
        acc.y += nm * v.y;
    }
    float di = dinv[n];
    float d2 = di * di;
    float2 hv = T2[(size_t)n * 64 + lane];
    acc.x += d2 * hv.x;
    acc.y += d2 * hv.y;
    float2 b2 = ((const float2*)bias)[lane];
    acc.x += b2.x;
    acc.y += b2.y;
    if (relu) { acc.x = fmaxf(acc.x, 0.f); acc.y = fmaxf(acc.y, 0.f); }
    ((float2*)O)[(size_t)n * 64 + lane] = acc;
}

// ---------------- pooling: batch is sorted -> run-length accumulate, few atomics ----------------
__global__ __launch_bounds__(128) void k_pool(const float* __restrict__ Hm, const int* __restrict__ batch,
                                              float* __restrict__ pooled, float* __restrict__ gcnt) {
    int j = threadIdx.x;
    int n0 = blockIdx.x * 64;
    int nend = n0 + 64; if (nend > NN) nend = NN;
    float acc = 0.f;
    int gcur = batch[n0];
    int run = 0;
    for (int n = n0; n < nend; n++) {
        int g = batch[n];
        if (g != gcur) {
            atomicAdd(&pooled[gcur * HH + j], acc);
            if (j == 0) atomicAdd(&gcnt[gcur], (float)run);
            acc = 0.f; run = 0; gcur = g;
        }
        acc += Hm[(size_t)n * HH + j];
        run++;
    }
    atomicAdd(&pooled[gcur * HH + j], acc);
    if (j == 0) atomicAdd(&gcnt[gcur], (float)run);
}

// ---------------- classifier: out[g,c] = bc[c] + sum_k (pooled[g,k]/cnt[g]) * Wc[k,c] ----------------
__global__ void k_classify(const float* __restrict__ pooled, const float* __restrict__ gcnt,
                           const float* __restrict__ Wc, const float* __restrict__ bc,
                           float* __restrict__ out) {
    int idx = blockIdx.x * blockDim.x + threadIdx.x;
    if (idx >= GG * CC) return;
    int g = idx >> 5, c = idx & 31;
    float inv = 1.f / fmaxf(gcnt[g], 1.f);
    float acc = bc[c];
    for (int k = 0; k < HH; k++) acc += pooled[g * HH + k] * inv * Wc[k * CC + c];
    out[idx] = acc;
}

extern "C" void kernel_launch(void* const* d_in, const int* in_sizes, int n_in,
                              void* d_out, int out_size, void* d_ws, size_t ws_size,
                              hipStream_t stream) {
    const float* x     = (const float*)d_in[0];
    const int*   ei    = (const int*)d_in[1];
    const int*   batch = (const int*)d_in[2];
    const float* W1 = (const float*)d_in[3];  const float* b1 = (const float*)d_in[4];
    const float* W2 = (const float*)d_in[5];  const float* b2 = (const float*)d_in[6];
    const float* W3 = (const float*)d_in[7];  const float* b3 = (const float*)d_in[8];
    const float* Wc = (const float*)d_in[9];  const float* bc = (const float*)d_in[10];
    float* out = (float*)d_out;

    const int* src = ei;
    const int* dst = ei + EE;

    char* w = (char*)d_ws;
    float* hA       = (float*)w;  w += (size_t)NN * HH * sizeof(float);   // 51.2 MB
    float* hB       = (float*)w;  w += (size_t)NN * HH * sizeof(float);   // 51.2 MB
    float* dinv     = (float*)w;  w += (size_t)NN * sizeof(float);
    float* csr_norm = (float*)w;  w += (size_t)EE * sizeof(float);
    int*   csr_src  = (int*)w;    w += (size_t)EE * sizeof(int);
    int*   row_off  = (int*)w;    w += (size_t)(NN + 1) * sizeof(int);
    int*   counts   = (int*)w;    w += (size_t)NN * sizeof(int);
    int*   cursor   = (int*)w;    w += (size_t)NN * sizeof(int);
    float* pooled   = (float*)w;  w += (size_t)GG * HH * sizeof(float);
    float* gcnt     = (float*)w;  w += (size_t)GG * sizeof(float);

    // graph structure (rebuilt every call; deterministic work)
    k_init   <<<(NN + 255) / 256, 256, 0, stream>>>(counts, cursor, pooled, gcnt);
    k_count  <<<(EE + 255) / 256, 256, 0, stream>>>(dst, counts);
    k_dinv   <<<(NN + 255) / 256, 256, 0, stream>>>(counts, dinv);
    k_scan   <<<1, 1024, 0, stream>>>(counts, row_off);
    k_scatter<<<(EE + 255) / 256, 256, 0, stream>>>(src, dst, dinv, row_off, cursor, csr_src, csr_norm);

    const int gemm_grid = NN / 32;            // 3125 (N % 32 == 0)
    const int agg_grid  = NN * 64 / 256;      // 25000 (one wave per node)

    // layer 1: x -> hA (gemm) -> hB (agg+bias+relu)
    k_gemm<<<gemm_grid, 256, 0, stream>>>(x, W1, hA);
    k_agg <<<agg_grid, 256, 0, stream>>>(hA, hB, row_off, csr_src, csr_norm, dinv, b1, 1);
    // layer 2
    k_gemm<<<gemm_grid, 256, 0, stream>>>(hB, W2, hA);
    k_agg <<<agg_grid, 256, 0, stream>>>(hA, hB, row_off, csr_src, csr_norm, dinv, b2, 1);
    // layer 3 (no relu)
    k_gemm<<<gemm_grid, 256, 0, stream>>>(hB, W3, hA);
    k_agg <<<agg_grid, 256, 0, stream>>>(hA, hB, row_off, csr_src, csr_norm, dinv, b3, 0);

    // pool + classify
    k_pool<<<(NN + 63) / 64, 128, 0, stream>>>(hB, batch, pooled, gcnt);
    k_classify<<<(GG * CC + 255) / 256, 256, 0, stream>>>(pooled, gcnt, Wc, bc, out);
}

// Round 2
// 816.563 us; speedup vs baseline: 1.2194x; 1.2194x over previous
//
#include <hip/hip_runtime.h>
#include <hip/hip_bf16.h>
#include <hip/hip_fp16.h>

#define NN 100000
#define EE 1600000
#define HH 128
#define GG 64
#define CC 32

// ---------------- init: zero counters/accumulators ----------------
__global__ void k_init(int* __restrict__ counts, int* __restrict__ cursor,
                       float* __restrict__ pooled, float* __restrict__ gcnt) {
    int i = blockIdx.x * blockDim.x + threadIdx.x;
    if (i < NN) { counts[i] = 0; cursor[i] = 0; }
    if (i < GG * HH) pooled[i] = 0.f;
    if (i < GG) gcnt[i] = 0.f;
}

// ---------------- in-degree histogram ----------------
__global__ void k_count(const int* __restrict__ dst, int* __restrict__ counts) {
    int e = blockIdx.x * blockDim.x + threadIdx.x;
    if (e < EE) atomicAdd(&counts[dst[e]], 1);
}

// ---------------- dinv = rsqrt(indeg + 1) ----------------
__global__ void k_dinv(const int* __restrict__ counts, float* __restrict__ dinv) {
    int i = blockIdx.x * blockDim.x + threadIdx.x;
    if (i < NN) dinv[i] = rsqrtf((float)counts[i] + 1.0f);
}

// ---------------- 3-phase coalesced exclusive scan of counts -> row_off ----------------
#define SCAN_B 1024
#define SCAN_NB ((NN + SCAN_B - 1) / SCAN_B)   // 98
__global__ __launch_bounds__(SCAN_B) void k_psum(const int* __restrict__ counts, int* __restrict__ bsum) {
    __shared__ int red[SCAN_B];
    int i = blockIdx.x * SCAN_B + threadIdx.x;
    red[threadIdx.x] = (i < NN) ? counts[i] : 0;
    __syncthreads();
    for (int off = SCAN_B / 2; off > 0; off >>= 1) {
        if (threadIdx.x < off) red[threadIdx.x] += red[threadIdx.x + off];
        __syncthreads();
    }
    if (threadIdx.x == 0) bsum[blockIdx.x] = red[0];
}
__global__ __launch_bounds__(128) void k_bscan(const int* __restrict__ bsum, int* __restrict__ boff) {
    __shared__ int s[128];
    int t = threadIdx.x;
    s[t] = (t < SCAN_NB) ? bsum[t] : 0;
    __syncthreads();
    for (int off = 1; off < 128; off <<= 1) {
        int tmp = (t >= off) ? s[t - off] : 0;
        __syncthreads();
        s[t] += tmp;
        __syncthreads();
    }
    if (t < SCAN_NB) boff[t] = s[t] - bsum[t];   // exclusive
}
__global__ __launch_bounds__(SCAN_B) void k_local(const int* __restrict__ counts, const int* __restrict__ boff,
                                                  int* __restrict__ row_off) {
    __shared__ int s[SCAN_B];
    int i = blockIdx.x * SCAN_B + threadIdx.x;
    int t = threadIdx.x;
    int v = (i < NN) ? counts[i] : 0;
    s[t] = v;
    __syncthreads();
    for (int off = 1; off < SCAN_B; off <<= 1) {
        int tmp = (t >= off) ? s[t - off] : 0;
        __syncthreads();
        s[t] += tmp;
        __syncthreads();
    }
    if (i < NN) row_off[i] = boff[blockIdx.x] + s[t] - v;
    if (i == NN - 1) row_off[NN] = EE;
}

// ---------------- scatter edges into CSR buckets ----------------
__global__ void k_scatter(const int* __restrict__ src, const int* __restrict__ dst,
                          const float* __restrict__ dinv, const int* __restrict__ row_off,
                          int* __restrict__ cursor, int* __restrict__ csr_src,
                          float* __restrict__ csr_norm) {
    int e = blockIdx.x * blockDim.x + threadIdx.x;
    if (e >= EE) return;
    int d = dst[e], s = src[e];
    int pos = row_off[d] + atomicAdd(&cursor[d], 1);
    csr_src[pos] = s;
    csr_norm[pos] = dinv[s] * dinv[d];
}

// ---------------- GEMM: T[N,128](fp16) = X[N,128](fp32) @ W[128,128](fp32) ----------------
__global__ __launch_bounds__(256) void k_gemm(const float* __restrict__ X, const float* __restrict__ W,
                                              __half* __restrict__ Y) {
    __shared__ float sW[HH * HH];     // 64 KB
    __shared__ float sX[32 * HH];     // 16 KB
    int tid = threadIdx.x;
    const float4* W4 = (const float4*)W;
    float4* sW4 = (float4*)sW;
    #pragma unroll
    for (int i = 0; i < 16; i++) sW4[tid + i * 256] = W4[tid + i * 256];
    size_t row0 = (size_t)blockIdx.x * 32;
    const float4* X4 = (const float4*)(X + row0 * HH);
    float4* sX4 = (float4*)sX;
    #pragma unroll
    for (int i = 0; i < 4; i++) sX4[tid + i * 256] = X4[tid + i * 256];
    __syncthreads();

    int j  = (tid & 31) * 4;
    int r0 = tid >> 5;
    float acc[4][4];
    #pragma unroll
    for (int r = 0; r < 4; r++)
        #pragma unroll
        for (int c = 0; c < 4; c++) acc[r][c] = 0.f;

    for (int k = 0; k < HH; k += 4) {
        float4 w[4];
        #pragma unroll
        for (int kk = 0; kk < 4; kk++) w[kk] = *(const float4*)&sW[(k + kk) * HH + j];
        #pragma unroll
        for (int r = 0; r < 4; r++) {
            float4 xv = *(const float4*)&sX[(r0 + r * 8) * HH + k];
            float xs[4] = {xv.x, xv.y, xv.z, xv.w};
            #pragma unroll
            for (int kk = 0; kk < 4; kk++) {
                acc[r][0] += xs[kk] * w[kk].x;
                acc[r][1] += xs[kk] * w[kk].y;
                acc[r][2] += xs[kk] * w[kk].z;
                acc[r][3] += xs[kk] * w[kk].w;
            }
        }
    }
    #pragma unroll
    for (int r = 0; r < 4; r++) {
        __half2 p0 = __floats2half2_rn(acc[r][0], acc[r][1]);
        __half2 p1 = __floats2half2_rn(acc[r][2], acc[r][3]);
        size_t base = (row0 + r0 + r * 8) * HH + j;
        *(__half2*)&Y[base]     = p0;
        *(__half2*)&Y[base + 2] = p1;
    }
}

// ---------------- aggregation: O[n](fp32) = relu?( b + dinv[n]^2*T[n] + sum norm*T[src] ), T fp16 ----------------
__global__ __launch_bounds__(256) void k_agg(const __half* __restrict__ T, float* __restrict__ O,
                                             const int* __restrict__ row_off, const int* __restrict__ csr_src,
                                             const float* __restrict__ csr_norm, const float* __restrict__ dinv,
                                             const float* __restrict__ bias, int relu) {
    int gt = blockIdx.x * blockDim.x + threadIdx.x;
    int n = gt >> 6;
    int lane = threadIdx.x & 63;
    if (n >= NN) return;
    int beg = row_off[n], end = row_off[n + 1];
    const __half2* T2 = (const __half2*)T;
    float2 acc = make_float2(0.f, 0.f);
    for (int p = beg; p < end; p++) {
        int s = csr_src[p];
        float nm = csr_norm[p];
        float2 v = __half22float2(T2[(size_t)s * 64 + lane]);
        acc.x += nm * v.x;
        acc.y += nm * v.y;
    }
    float di = dinv[n];
    float d2 = di * di;
    float2 hv = __half22float2(T2[(size_t)n * 64 + lane]);
    acc.x += d2 * hv.x;
    acc.y += d2 * hv.y;
    float2 b2 = ((const float2*)bias)[lane];
    acc.x += b2.x;
    acc.y += b2.y;
    if (relu) { acc.x = fmaxf(acc.x, 0.f); acc.y = fmaxf(acc.y, 0.f); }
    ((float2*)O)[(size_t)n * 64 + lane] = acc;
}

// ---------------- pooling: batch sorted -> run-length accumulate ----------------
__global__ __launch_bounds__(128) void k_pool(const float* __restrict__ Hm, const int* __restrict__ batch,
                                              float* __restrict__ pooled, float* __restrict__ gcnt) {
    int j = threadIdx.x;
    int n0 = blockIdx.x * 64;
    int nend = n0 + 64; if (nend > NN) nend = NN;
    float acc = 0.f;
    int gcur = batch[n0];
    int run = 0;
    for (int n = n0; n < nend; n++) {
        int g = batch[n];
        if (g != gcur) {
            atomicAdd(&pooled[gcur * HH + j], acc);
            if (j == 0) atomicAdd(&gcnt[gcur], (float)run);
            acc = 0.f; run = 0; gcur = g;
        }
        acc += Hm[(size_t)n * HH + j];
        run++;
    }
    atomicAdd(&pooled[gcur * HH + j], acc);
    if (j == 0) atomicAdd(&gcnt[gcur], (float)run);
}

// ---------------- classifier ----------------
__global__ void k_classify(const float* __restrict__ pooled, const float* __restrict__ gcnt,
                           const float* __restrict__ Wc, const float* __restrict__ bc,
                           float* __restrict__ out) {
    int idx = blockIdx.x * blockDim.x + threadIdx.x;
    if (idx >= GG * CC) return;
    int g = idx >> 5, c = idx & 31;
    float inv = 1.f / fmaxf(gcnt[g], 1.f);
    float acc = bc[c];
    for (int k = 0; k < HH; k++) acc += pooled[g * HH + k] * inv * Wc[k * CC + c];
    out[idx] = acc;
}

extern "C" void kernel_launch(void* const* d_in, const int* in_sizes, int n_in,
                              void* d_out, int out_size, void* d_ws, size_t ws_size,
                              hipStream_t stream) {
    const float* x     = (const float*)d_in[0];
    const int*   ei    = (const int*)d_in[1];
    const int*   batch = (const int*)d_in[2];
    const float* W1 = (const float*)d_in[3];  const float* b1 = (const float*)d_in[4];
    const float* W2 = (const float*)d_in[5];  const float* b2 = (const float*)d_in[6];
    const float* W3 = (const float*)d_in[7];  const float* b3 = (const float*)d_in[8];
    const float* Wc = (const float*)d_in[9];  const float* bc = (const float*)d_in[10];
    float* out = (float*)d_out;

    const int* src = ei;
    const int* dst = ei + EE;

    char* w = (char*)d_ws;
    float*  h        = (float*)w;   w += (size_t)NN * HH * sizeof(float);    // 51.2 MB
    __half* t        = (__half*)w;  w += (size_t)NN * HH * sizeof(__half);   // 25.6 MB
    float*  dinv     = (float*)w;   w += (size_t)NN * sizeof(float);
    float*  csr_norm = (float*)w;   w += (size_t)EE * sizeof(float);
    int*    csr_src  = (int*)w;     w += (size_t)EE * sizeof(int);
    int*    row_off  = (int*)w;     w += (size_t)(NN + 1) * sizeof(int);
    int*    counts   = (int*)w;     w += (size_t)NN * sizeof(int);
    int*    cursor   = (int*)w;     w += (size_t)NN * sizeof(int);
    int*    bsum     = (int*)w;     w += (size_t)SCAN_NB * sizeof(int);
    int*    boff     = (int*)w;     w += (size_t)SCAN_NB * sizeof(int);
    float*  pooled   = (float*)w;   w += (size_t)GG * HH * sizeof(float);
    float*  gcnt     = (float*)w;   w += (size_t)GG * sizeof(float);

    // graph structure (rebuilt every call; deterministic work)
    k_init   <<<(NN + 255) / 256, 256, 0, stream>>>(counts, cursor, pooled, gcnt);
    k_count  <<<(EE + 255) / 256, 256, 0, stream>>>(dst, counts);
    k_dinv   <<<(NN + 255) / 256, 256, 0, stream>>>(counts, dinv);
    k_psum   <<<SCAN_NB, SCAN_B, 0, stream>>>(counts, bsum);
    k_bscan  <<<1, 128, 0, stream>>>(bsum, boff);
    k_local  <<<SCAN_NB, SCAN_B, 0, stream>>>(counts, boff, row_off);
    k_scatter<<<(EE + 255) / 256, 256, 0, stream>>>(src, dst, dinv, row_off, cursor, csr_src, csr_norm);

    const int gemm_grid = NN / 32;            // 3125
    const int agg_grid  = NN * 64 / 256;      // 25000

    // layer 1: x -> t (gemm, fp16 out) -> h (agg+bias+relu, fp32)
    k_gemm<<<gemm_grid, 256, 0, stream>>>(x, W1, t);
    k_agg <<<agg_grid, 256, 0, stream>>>(t, h, row_off, csr_src, csr_norm, dinv, b1, 1);
    // layer 2
    k_gemm<<<gemm_grid, 256, 0, stream>>>(h, W2, t);
    k_agg <<<agg_grid, 256, 0, stream>>>(t, h, row_off, csr_src, csr_norm, dinv, b2, 1);
    // layer 3 (no relu)
    k_gemm<<<gemm_grid, 256, 0, stream>>>(h, W3, t);
    k_agg <<<agg_grid, 256, 0, stream>>>(t, h, row_off, csr_src, csr_norm, dinv, b3, 0);

    // pool + classify
    k_pool<<<(NN + 63) / 64, 128, 0, stream>>>(h, batch, pooled, gcnt);
    k_classify<<<(GG * CC + 255) / 256, 256, 0, stream>>>(pooled, gcnt, Wc, bc, out);
}

// Round 4
// 556.250 us; speedup vs baseline: 1.7900x; 1.4680x over previous
//
#include <hip/hip_runtime.h>
#include <hip/hip_bf16.h>
#include <hip/hip_fp16.h>

#define NN 100000
#define EE 1600000
#define HH 128
#define GG 64
#define CC 32
#define ETOT (EE + NN)   // edges + self-loops

// ---------------- init: counts=1 (self-loop), zero accumulators ----------------
__global__ void k_init(int* __restrict__ counts, float* __restrict__ pooled, float* __restrict__ gcnt) {
    int i = blockIdx.x * blockDim.x + threadIdx.x;
    if (i < NN) counts[i] = 1;
    if (i < GG * HH) pooled[i] = 0.f;
    if (i < GG) gcnt[i] = 0.f;
}

// ---------------- in-degree histogram ----------------
__global__ void k_count(const int* __restrict__ dst, int* __restrict__ counts) {
    int e = blockIdx.x * blockDim.x + threadIdx.x;
    if (e < EE) atomicAdd(&counts[dst[e]], 1);
}

// ---------------- dinv = rsqrt(counts) (counts = indeg + 1 already) ----------------
__global__ void k_dinv(const int* __restrict__ counts, float* __restrict__ dinv) {
    int i = blockIdx.x * blockDim.x + threadIdx.x;
    if (i < NN) dinv[i] = rsqrtf((float)counts[i]);
}

// ---------------- 3-phase coalesced exclusive scan of counts -> row_off ----------------
#define SCAN_B 1024
#define SCAN_NB ((NN + SCAN_B - 1) / SCAN_B)   // 98
__global__ __launch_bounds__(SCAN_B) void k_psum(const int* __restrict__ counts, int* __restrict__ bsum) {
    __shared__ int red[SCAN_B];
    int i = blockIdx.x * SCAN_B + threadIdx.x;
    red[threadIdx.x] = (i < NN) ? counts[i] : 0;
    __syncthreads();
    for (int off = SCAN_B / 2; off > 0; off >>= 1) {
        if (threadIdx.x < off) red[threadIdx.x] += red[threadIdx.x + off];
        __syncthreads();
    }
    if (threadIdx.x == 0) bsum[blockIdx.x] = red[0];
}
__global__ __launch_bounds__(128) void k_bscan(const int* __restrict__ bsum, int* __restrict__ boff) {
    __shared__ int s[128];
    int t = threadIdx.x;
    s[t] = (t < SCAN_NB) ? bsum[t] : 0;
    __syncthreads();
    for (int off = 1; off < 128; off <<= 1) {
        int tmp = (t >= off) ? s[t - off] : 0;
        __syncthreads();
        s[t] += tmp;
        __syncthreads();
    }
    if (t < SCAN_NB) boff[t] = s[t] - bsum[t];   // exclusive
}
__global__ __launch_bounds__(SCAN_B) void k_local(const int* __restrict__ counts, const int* __restrict__ boff,
                                                  int* __restrict__ row_off) {
    __shared__ int s[SCAN_B];
    int i = blockIdx.x * SCAN_B + threadIdx.x;
    int t = threadIdx.x;
    int v = (i < NN) ? counts[i] : 0;
    s[t] = v;
    __syncthreads();
    for (int off = 1; off < SCAN_B; off <<= 1) {
        int tmp = (t >= off) ? s[t - off] : 0;
        __syncthreads();
        s[t] += tmp;
        __syncthreads();
    }
    if (i < NN) row_off[i] = boff[blockIdx.x] + s[t] - v;
    if (i == NN - 1) row_off[NN] = ETOT;
}

// ---------------- write self-loop edge in slot 0, set cursor=1 ----------------
__global__ void k_self(const float* __restrict__ dinv, const int* __restrict__ row_off,
                       int* __restrict__ cursor, int2* __restrict__ csr_ed) {
    int n = blockIdx.x * blockDim.x + threadIdx.x;
    if (n >= NN) return;
    float di = dinv[n];
    csr_ed[row_off[n]] = make_int2(n, __float_as_int(di * di));
    cursor[n] = 1;
}

// ---------------- scatter edges into CSR buckets (packed src+norm) ----------------
__global__ void k_scatter(const int* __restrict__ src, const int* __restrict__ dst,
                          const float* __restrict__ dinv, const int* __restrict__ row_off,
                          int* __restrict__ cursor, int2* __restrict__ csr_ed) {
    int e = blockIdx.x * blockDim.x + threadIdx.x;
    if (e >= EE) return;
    int d = dst[e], s = src[e];
    int pos = row_off[d] + atomicAdd(&cursor[d], 1);
    csr_ed[pos] = make_int2(s, __float_as_int(dinv[s] * dinv[d]));
}

// ---------------- GEMM: T[N,128](fp16) = X[N,128](fp32) @ W[128,128](fp32) ----------------
__global__ __launch_bounds__(256) void k_gemm(const float* __restrict__ X, const float* __restrict__ W,
                                              __half* __restrict__ Y) {
    __shared__ float sW[HH * HH];     // 64 KB
    __shared__ float sX[32 * HH];     // 16 KB
    int tid = threadIdx.x;
    const float4* W4 = (const float4*)W;
    float4* sW4 = (float4*)sW;
    #pragma unroll
    for (int i = 0; i < 16; i++) sW4[tid + i * 256] = W4[tid + i * 256];
    size_t row0 = (size_t)blockIdx.x * 32;
    const float4* X4 = (const float4*)(X + row0 * HH);
    float4* sX4 = (float4*)sX;
    #pragma unroll
    for (int i = 0; i < 4; i++) sX4[tid + i * 256] = X4[tid + i * 256];
    __syncthreads();

    int j  = (tid & 31) * 4;
    int r0 = tid >> 5;
    float acc[4][4];
    #pragma unroll
    for (int r = 0; r < 4; r++)
        #pragma unroll
        for (int c = 0; c < 4; c++) acc[r][c] = 0.f;

    for (int k = 0; k < HH; k += 4) {
        float4 w[4];
        #pragma unroll
        for (int kk = 0; kk < 4; kk++) w[kk] = *(const float4*)&sW[(k + kk) * HH + j];
        #pragma unroll
        for (int r = 0; r < 4; r++) {
            float4 xv = *(const float4*)&sX[(r0 + r * 8) * HH + k];
            float xs[4] = {xv.x, xv.y, xv.z, xv.w};
            #pragma unroll
            for (int kk = 0; kk < 4; kk++) {
                acc[r][0] += xs[kk] * w[kk].x;
                acc[r][1] += xs[kk] * w[kk].y;
                acc[r][2] += xs[kk] * w[kk].z;
                acc[r][3] += xs[kk] * w[kk].w;
            }
        }
    }
    #pragma unroll
    for (int r = 0; r < 4; r++) {
        __half2 p0 = __floats2half2_rn(acc[r][0], acc[r][1]);
        __half2 p1 = __floats2half2_rn(acc[r][2], acc[r][3]);
        size_t base = (row0 + r0 + r * 8) * HH + j;
        *(__half2*)&Y[base]     = p0;
        *(__half2*)&Y[base + 2] = p1;
    }
}

// ---------------- aggregation: 4 edges per wave-load ----------------
// wave = 1 node; lane = (g 0..3 edge slot) x (li 0..15 col group of 8 fp16 = 16B)
// O[n] = relu?( bias + sum_{csr edges incl self} norm * T[src] )
__global__ __launch_bounds__(256) void k_agg(const __half* __restrict__ T, float* __restrict__ O,
                                             const int* __restrict__ row_off,
                                             const int2* __restrict__ csr_ed,
                                             const float* __restrict__ bias, int relu) {
    int gt = blockIdx.x * blockDim.x + threadIdx.x;
    int n = gt >> 6;
    if (n >= NN) return;
    int lane = threadIdx.x & 63;
    int g  = lane >> 4;      // edge slot within iteration
    int li = lane & 15;      // column group (8 halves = 16B)

    int beg = row_off[n], end = row_off[n + 1];
    int nit = (end - beg + 3) >> 2;          // wave-uniform trip count (>=1: self edge)

    float acc[8];
    #pragma unroll
    for (int c = 0; c < 8; c++) acc[c] = 0.f;

    int p = beg + g;
    #pragma unroll 2
    for (int i = 0; i < nit; i++, p += 4) {
        bool v = p < end;
        int2 ed = csr_ed[v ? p : beg];       // always-valid address, predicated weight
        float nm = v ? __int_as_float(ed.y) : 0.f;
        const float4* rowp = (const float4*)(T + (size_t)ed.x * HH);
        float4 raw = rowp[li];               // 16B = 8 fp16
        const __half2* hp = (const __half2*)&raw;
        float2 f0 = __half22float2(hp[0]);
        float2 f1 = __half22float2(hp[1]);
        float2 f2 = __half22float2(hp[2]);
        float2 f3 = __half22float2(hp[3]);
        acc[0] += nm * f0.x;  acc[1] += nm * f0.y;
        acc[2] += nm * f1.x;  acc[3] += nm * f1.y;
        acc[4] += nm * f2.x;  acc[5] += nm * f2.y;
        acc[6] += nm * f3.x;  acc[7] += nm * f3.y;
    }

    // reduce across the 4 edge slots (lanes l, l^16, l^32, l^48)
    #pragma unroll
    for (int c = 0; c < 8; c++) {
        acc[c] += __shfl_xor(acc[c], 16, 64);
        acc[c] += __shfl_xor(acc[c], 32, 64);
    }

    if (g == 0) {
        const float4* B4 = (const float4*)bias;
        float4 b0 = B4[li * 2], b1 = B4[li * 2 + 1];
        float4 o0 = make_float4(acc[0] + b0.x, acc[1] + b0.y, acc[2] + b0.z, acc[3] + b0.w);
        float4 o1 = make_float4(acc[4] + b1.x, acc[5] + b1.y, acc[6] + b1.z, acc[7] + b1.w);
        if (relu) {
            o0.x = fmaxf(o0.x, 0.f); o0.y = fmaxf(o0.y, 0.f); o0.z = fmaxf(o0.z, 0.f); o0.w = fmaxf(o0.w, 0.f);
            o1.x = fmaxf(o1.x, 0.f); o1.y = fmaxf(o1.y, 0.f); o1.z = fmaxf(o1.z, 0.f); o1.w = fmaxf(o1.w, 0.f);
        }
        float4* Op = (float4*)(O + (size_t)n * HH + li * 8);
        Op[0] = o0; Op[1] = o1;
    }
}

// ---------------- pooling: batch sorted -> run-length accumulate ----------------
__global__ __launch_bounds__(128) void k_pool(const float* __restrict__ Hm, const int* __restrict__ batch,
                                              float* __restrict__ pooled, float* __restrict__ gcnt) {
    int j = threadIdx.x;
    int n0 = blockIdx.x * 64;
    int nend = n0 + 64; if (nend > NN) nend = NN;
    float acc = 0.f;
    int gcur = batch[n0];
    int run = 0;
    for (int n = n0; n < nend; n++) {
        int g = batch[n];
        if (g != gcur) {
            atomicAdd(&pooled[gcur * HH + j], acc);
            if (j == 0) atomicAdd(&gcnt[gcur], (float)run);
            acc = 0.f; run = 0; gcur = g;
        }
        acc += Hm[(size_t)n * HH + j];
        run++;
    }
    atomicAdd(&pooled[gcur * HH + j], acc);
    if (j == 0) atomicAdd(&gcnt[gcur], (float)run);
}

// ---------------- classifier ----------------
__global__ void k_classify(const float* __restrict__ pooled, const float* __restrict__ gcnt,
                           const float* __restrict__ Wc, const float* __restrict__ bc,
                           float* __restrict__ out) {
    int idx = blockIdx.x * blockDim.x + threadIdx.x;
    if (idx >= GG * CC) return;
    int g = idx >> 5, c = idx & 31;
    float inv = 1.f / fmaxf(gcnt[g], 1.f);
    float acc = bc[c];
    for (int k = 0; k < HH; k++) acc += pooled[g * HH + k] * inv * Wc[k * CC + c];
    out[idx] = acc;
}

extern "C" void kernel_launch(void* const* d_in, const int* in_sizes, int n_in,
                              void* d_out, int out_size, void* d_ws, size_t ws_size,
                              hipStream_t stream) {
    const float* x     = (const float*)d_in[0];
    const int*   ei    = (const int*)d_in[1];
    const int*   batch = (const int*)d_in[2];
    const float* W1 = (const float*)d_in[3];  const float* b1 = (const float*)d_in[4];
    const float* W2 = (const float*)d_in[5];  const float* b2 = (const float*)d_in[6];
    const float* W3 = (const float*)d_in[7];  const float* b3 = (const float*)d_in[8];
    const float* Wc = (const float*)d_in[9];  const float* bc = (const float*)d_in[10];
    float* out = (float*)d_out;

    const int* src = ei;
    const int* dst = ei + EE;

    char* w = (char*)d_ws;
    float*  h        = (float*)w;   w += (size_t)NN * HH * sizeof(float);    // 51.2 MB
    __half* t        = (__half*)w;  w += (size_t)NN * HH * sizeof(__half);   // 25.6 MB
    float*  dinv     = (float*)w;   w += (size_t)NN * sizeof(float);
    int2*   csr_ed   = (int2*)w;    w += (size_t)ETOT * sizeof(int2);        // 13.6 MB
    int*    row_off  = (int*)w;     w += (size_t)(NN + 1) * sizeof(int);
    int*    counts   = (int*)w;     w += (size_t)NN * sizeof(int);
    int*    cursor   = (int*)w;     w += (size_t)NN * sizeof(int);
    int*    bsum     = (int*)w;     w += (size_t)SCAN_NB * sizeof(int);
    int*    boff     = (int*)w;     w += (size_t)SCAN_NB * sizeof(int);
    float*  pooled   = (float*)w;   w += (size_t)GG * HH * sizeof(float);
    float*  gcnt     = (float*)w;   w += (size_t)GG * sizeof(float);

    // graph structure (rebuilt every call; deterministic work)
    k_init   <<<(NN + 255) / 256, 256, 0, stream>>>(counts, pooled, gcnt);
    k_count  <<<(EE + 255) / 256, 256, 0, stream>>>(dst, counts);
    k_dinv   <<<(NN + 255) / 256, 256, 0, stream>>>(counts, dinv);
    k_psum   <<<SCAN_NB, SCAN_B, 0, stream>>>(counts, bsum);
    k_bscan  <<<1, 128, 0, stream>>>(bsum, boff);
    k_local  <<<SCAN_NB, SCAN_B, 0, stream>>>(counts, boff, row_off);
    k_self   <<<(NN + 255) / 256, 256, 0, stream>>>(dinv, row_off, cursor, csr_ed);
    k_scatter<<<(EE + 255) / 256, 256, 0, stream>>>(src, dst, dinv, row_off, cursor, csr_ed);

    const int gemm_grid = NN / 32;            // 3125
    const int agg_grid  = NN * 64 / 256;      // 25000 (one wave per node)

    // layer 1: x -> t (gemm, fp16 out) -> h (agg+bias+relu, fp32)
    k_gemm<<<gemm_grid, 256, 0, stream>>>(x, W1, t);
    k_agg <<<agg_grid, 256, 0, stream>>>(t, h, row_off, csr_ed, b1, 1);
    // layer 2
    k_gemm<<<gemm_grid, 256, 0, stream>>>(h, W2, t);
    k_agg <<<agg_grid, 256, 0, stream>>>(t, h, row_off, csr_ed, b2, 1);
    // layer 3 (no relu)
    k_gemm<<<gemm_grid, 256, 0, stream>>>(h, W3, t);
    k_agg <<<agg_grid, 256, 0, stream>>>(t, h, row_off, csr_ed, b3, 0);

    // pool + classify
    k_pool<<<(NN + 63) / 64, 128, 0, stream>>>(h, batch, pooled, gcnt);
    k_classify<<<(GG * CC + 255) / 256, 256, 0, stream>>>(pooled, gcnt, Wc, bc, out);
}

// Round 5
// 469.581 us; speedup vs baseline: 2.1204x; 1.1846x over previous
//
#include <hip/hip_runtime.h>
#include <hip/hip_fp16.h>

#define NN 100000
#define EE 1600000
#define HH 128
#define GG 64
#define CC 32
#define ETOT (EE + NN)   // edges + self-loops

typedef _Float16 half8 __attribute__((ext_vector_type(8)));
typedef float f32x4 __attribute__((ext_vector_type(4)));

// ---------------- init: counts=1 (self-loop), zero accumulators ----------------
__global__ void k_init(int* __restrict__ counts, float* __restrict__ pooled, float* __restrict__ gcnt) {
    int i = blockIdx.x * blockDim.x + threadIdx.x;
    if (i < NN) counts[i] = 1;
    if (i < GG * HH) pooled[i] = 0.f;
    if (i < GG) gcnt[i] = 0.f;
}

// ---------------- in-degree histogram ----------------
__global__ void k_count(const int* __restrict__ dst, int* __restrict__ counts) {
    int e = blockIdx.x * blockDim.x + threadIdx.x;
    if (e < EE) atomicAdd(&counts[dst[e]], 1);
}

// ---------------- dinv = rsqrt(counts) ----------------
__global__ void k_dinv(const int* __restrict__ counts, float* __restrict__ dinv) {
    int i = blockIdx.x * blockDim.x + threadIdx.x;
    if (i < NN) dinv[i] = rsqrtf((float)counts[i]);
}

// ---------------- x -> fp16 ----------------
__global__ void k_x16(const float* __restrict__ x, __half* __restrict__ x16) {
    int i = blockIdx.x * blockDim.x + threadIdx.x;     // 4 floats per thread
    if (i >= NN * HH / 4) return;
    float4 v = ((const float4*)x)[i];
    ((__half2*)x16)[i * 2]     = __floats2half2_rn(v.x, v.y);
    ((__half2*)x16)[i * 2 + 1] = __floats2half2_rn(v.z, v.w);
}

// ---------------- W[k][n] fp32 -> Wt[n][k] fp16 (3 layers) ----------------
__global__ __launch_bounds__(256) void k_prepw(const float* __restrict__ W1, const float* __restrict__ W2,
                                               const float* __restrict__ W3, __half* __restrict__ wt) {
    __shared__ float sW[HH * (HH + 1)];
    const float* W = (blockIdx.x == 0) ? W1 : (blockIdx.x == 1) ? W2 : W3;
    __half* out = wt + (size_t)blockIdx.x * HH * HH;
    int t = threadIdx.x;
    #pragma unroll 4
    for (int i = 0; i < 64; i++) {
        int idx = i * 256 + t;
        sW[(idx >> 7) * (HH + 1) + (idx & 127)] = W[idx];
    }
    __syncthreads();
    #pragma unroll 4
    for (int i = 0; i < 64; i++) {
        int o = i * 256 + t;
        int n = o >> 7, k = o & 127;
        out[o] = __float2half(sW[k * (HH + 1) + n]);
    }
}

// ---------------- 3-phase coalesced exclusive scan of counts -> row_off ----------------
#define SCAN_B 1024
#define SCAN_NB ((NN + SCAN_B - 1) / SCAN_B)   // 98
__global__ __launch_bounds__(SCAN_B) void k_psum(const int* __restrict__ counts, int* __restrict__ bsum) {
    __shared__ int red[SCAN_B];
    int i = blockIdx.x * SCAN_B + threadIdx.x;
    red[threadIdx.x] = (i < NN) ? counts[i] : 0;
    __syncthreads();
    for (int off = SCAN_B / 2; off > 0; off >>= 1) {
        if (threadIdx.x < off) red[threadIdx.x] += red[threadIdx.x + off];
        __syncthreads();
    }
    if (threadIdx.x == 0) bsum[blockIdx.x] = red[0];
}
__global__ __launch_bounds__(128) void k_bscan(const int* __restrict__ bsum, int* __restrict__ boff) {
    __shared__ int s[128];
    int t = threadIdx.x;
    s[t] = (t < SCAN_NB) ? bsum[t] : 0;
    __syncthreads();
    for (int off = 1; off < 128; off <<= 1) {
        int tmp = (t >= off) ? s[t - off] : 0;
        __syncthreads();
        s[t] += tmp;
        __syncthreads();
    }
    if (t < SCAN_NB) boff[t] = s[t] - bsum[t];   // exclusive
}
__global__ __launch_bounds__(SCAN_B) void k_local(const int* __restrict__ counts, const int* __restrict__ boff,
                                                  int* __restrict__ row_off) {
    __shared__ int s[SCAN_B];
    int i = blockIdx.x * SCAN_B + threadIdx.x;
    int t = threadIdx.x;
    int v = (i < NN) ? counts[i] : 0;
    s[t] = v;
    __syncthreads();
    for (int off = 1; off < SCAN_B; off <<= 1) {
        int tmp = (t >= off) ? s[t - off] : 0;
        __syncthreads();
        s[t] += tmp;
        __syncthreads();
    }
    if (i < NN) row_off[i] = boff[blockIdx.x] + s[t] - v;
    if (i == NN - 1) row_off[NN] = ETOT;
}

// ---------------- self-loop edge in slot 0, cursor=1 ----------------
__global__ void k_self(const int* __restrict__ row_off, int* __restrict__ cursor, int* __restrict__ csr_src) {
    int n = blockIdx.x * blockDim.x + threadIdx.x;
    if (n >= NN) return;
    csr_src[row_off[n]] = n;
    cursor[n] = 1;
}

// ---------------- scatter edges (src only, 4B/edge) ----------------
__global__ void k_scatter(const int* __restrict__ src, const int* __restrict__ dst,
                          const int* __restrict__ row_off, int* __restrict__ cursor,
                          int* __restrict__ csr_src) {
    int e = blockIdx.x * blockDim.x + threadIdx.x;
    if (e >= EE) return;
    int d = dst[e];
    int pos = row_off[d] + atomicAdd(&cursor[d], 1);
    csr_src[pos] = src[e];
}

// ---------------- MFMA GEMM: T[r][c](fp16) = dinv[r] * (A[r][:] @ W)[c] ----------------
// A fp16 row-major [N][128]; Wt fp16 = W^T row-major [n][k]. 128x128 tile, 4 waves of 64x64.
// Fragments (16x16x32 f16): A-frag lane l: A[m0+(l&15)][k0+(l>>4)*8+j]; B-frag: Wt[n0+(l&15)][k0+(l>>4)*8+j]
// C/D: col = l&15, row = (l>>4)*4 + reg   (m89-verified set)
__global__ __launch_bounds__(256) void k_gemm(const __half* __restrict__ A, const __half* __restrict__ Wt,
                                              const float* __restrict__ dinv, __half* __restrict__ T) {
    __shared__ __align__(16) char sm[64 * 1024];
    char* sA = sm;                 // 128 rows x 256B, XOR-swizzled
    char* sB = sm + 32 * 1024;     // 128 rows x 256B, XOR-swizzled
    int tid = threadIdx.x;
    int r0 = blockIdx.x * 128;

    // stage A tile (clamp tail rows; content unused for rows >= NN)
    const char* Ab = (const char*)A;
    #pragma unroll
    for (int it = 0; it < 8; it++) {
        int p = (tid + it * 256) * 16;            // linear byte in tile
        int lrow = p >> 8;
        int grow = r0 + lrow; if (grow > NN - 1) grow = NN - 1;
        uint4 v = *(const uint4*)(Ab + (size_t)grow * 256 + (p & 255));
        *(uint4*)(sA + (p ^ ((lrow & 7) << 4))) = v;
    }
    const char* Wb = (const char*)Wt;
    #pragma unroll
    for (int it = 0; it < 8; it++) {
        int p = (tid + it * 256) * 16;
        int lrow = p >> 8;
        uint4 v = *(const uint4*)(Wb + p);
        *(uint4*)(sB + (p ^ ((lrow & 7) << 4))) = v;
    }
    __syncthreads();

    int w = tid >> 6;
    int lane = tid & 63;
    int q = lane >> 4;         // k-chunk quarter
    int ln = lane & 15;
    int wr = (w >> 1) * 64;    // wave row base in tile
    int wc = (w & 1) * 64;     // wave col base in tile

    f32x4 acc[4][4];
    #pragma unroll
    for (int a = 0; a < 4; a++)
        #pragma unroll
        for (int b = 0; b < 4; b++) acc[a][b] = (f32x4)0.f;

    #pragma unroll
    for (int ks = 0; ks < 4; ks++) {
        int koff = ks * 64 + q * 16;            // byte offset within 256B row
        half8 af[4], bf[4];
        #pragma unroll
        for (int mi = 0; mi < 4; mi++) {
            int row = wr + mi * 16 + ln;
            af[mi] = *(half8*)(sA + row * 256 + (koff ^ ((row & 7) << 4)));
        }
        #pragma unroll
        for (int ni = 0; ni < 4; ni++) {
            int row = wc + ni * 16 + ln;
            bf[ni] = *(half8*)(sB + row * 256 + (koff ^ ((row & 7) << 4)));
        }
        #pragma unroll
        for (int mi = 0; mi < 4; mi++)
            #pragma unroll
            for (int ni = 0; ni < 4; ni++)
                acc[mi][ni] = __builtin_amdgcn_mfma_f32_16x16x32_f16(af[mi], bf[ni], acc[mi][ni], 0, 0, 0);
    }

    // epilogue: scale by dinv[row], convert, store fp16
    float dv[4][4];
    #pragma unroll
    for (int mi = 0; mi < 4; mi++)
        #pragma unroll
        for (int r = 0; r < 4; r++) {
            int grow = r0 + wr + mi * 16 + q * 4 + r;
            dv[mi][r] = dinv[grow < NN ? grow : 0];
        }
    #pragma unroll
    for (int mi = 0; mi < 4; mi++) {
        #pragma unroll
        for (int r = 0; r < 4; r++) {
            int grow = r0 + wr + mi * 16 + q * 4 + r;
            if (grow < NN) {
                #pragma unroll
                for (int ni = 0; ni < 4; ni++) {
                    int gcol = wc + ni * 16 + ln;
                    T[(size_t)grow * HH + gcol] = __float2half(acc[mi][ni][r] * dv[mi][r]);
                }
            }
        }
    }
}

// ---------------- aggregation: O[n] = relu?( dinv[n]*sum_{csr} T'[src] + bias ), fp16 in/out ----------------
__global__ __launch_bounds__(256) void k_agg(const __half* __restrict__ T, __half* __restrict__ O,
                                             const int* __restrict__ row_off, const int* __restrict__ csr_src,
                                             const float* __restrict__ dinv,
                                             const float* __restrict__ bias, int relu) {
    int gt = blockIdx.x * blockDim.x + threadIdx.x;
    int n = gt >> 6;
    if (n >= NN) return;
    int lane = threadIdx.x & 63;
    int g  = lane >> 4;      // edge slot
    int li = lane & 15;      // 16B column group

    int beg = row_off[n], end = row_off[n + 1];
    int nit = (end - beg + 3) >> 2;          // >=1 (self edge)

    float acc[8];
    #pragma unroll
    for (int c = 0; c < 8; c++) acc[c] = 0.f;

    int p = beg + g;
    #pragma unroll 2
    for (int i = 0; i < nit; i++, p += 4) {
        bool v = p < end;
        int s = csr_src[v ? p : beg];
        float m = v ? 1.f : 0.f;
        uint4 raw = *(const uint4*)(T + (size_t)s * HH + li * 8);
        const __half2* hp = (const __half2*)&raw;
        float2 f0 = __half22float2(hp[0]);
        float2 f1 = __half22float2(hp[1]);
        float2 f2 = __half22float2(hp[2]);
        float2 f3 = __half22float2(hp[3]);
        acc[0] += m * f0.x;  acc[1] += m * f0.y;
        acc[2] += m * f1.x;  acc[3] += m * f1.y;
        acc[4] += m * f2.x;  acc[5] += m * f2.y;
        acc[6] += m * f3.x;  acc[7] += m * f3.y;
    }

    #pragma unroll
    for (int c = 0; c < 8; c++) {
        acc[c] += __shfl_xor(acc[c], 16, 64);
        acc[c] += __shfl_xor(acc[c], 32, 64);
    }

    if (g == 0) {
        float dn = dinv[n];
        const float4* B4 = (const float4*)bias;
        float4 b0 = B4[li * 2], b1 = B4[li * 2 + 1];
        float o0 = dn * acc[0] + b0.x, o1 = dn * acc[1] + b0.y;
        float o2 = dn * acc[2] + b0.z, o3 = dn * acc[3] + b0.w;
        float o4 = dn * acc[4] + b1.x, o5 = dn * acc[5] + b1.y;
        float o6 = dn * acc[6] + b1.z, o7 = dn * acc[7] + b1.w;
        if (relu) {
            o0 = fmaxf(o0, 0.f); o1 = fmaxf(o1, 0.f); o2 = fmaxf(o2, 0.f); o3 = fmaxf(o3, 0.f);
            o4 = fmaxf(o4, 0.f); o5 = fmaxf(o5, 0.f); o6 = fmaxf(o6, 0.f); o7 = fmaxf(o7, 0.f);
        }
        union { uint4 u; __half2 h2[4]; } pk;
        pk.h2[0] = __floats2half2_rn(o0, o1);
        pk.h2[1] = __floats2half2_rn(o2, o3);
        pk.h2[2] = __floats2half2_rn(o4, o5);
        pk.h2[3] = __floats2half2_rn(o6, o7);
        *(uint4*)(O + (size_t)n * HH + li * 8) = pk.u;
    }
}

// ---------------- pooling: batch sorted -> run-length accumulate (fp16 in) ----------------
__global__ __launch_bounds__(128) void k_pool(const __half* __restrict__ Hm, const int* __restrict__ batch,
                                              float* __restrict__ pooled, float* __restrict__ gcnt) {
    int j = threadIdx.x;
    int n0 = blockIdx.x * 64;
    int nend = n0 + 64; if (nend > NN) nend = NN;
    float acc = 0.f;
    int gcur = batch[n0];
    int run = 0;
    for (int n = n0; n < nend; n++) {
        int g = batch[n];
        if (g != gcur) {
            atomicAdd(&pooled[gcur * HH + j], acc);
            if (j == 0) atomicAdd(&gcnt[gcur], (float)run);
            acc = 0.f; run = 0; gcur = g;
        }
        acc += __half2float(Hm[(size_t)n * HH + j]);
        run++;
    }
    atomicAdd(&pooled[gcur * HH + j], acc);
    if (j == 0) atomicAdd(&gcnt[gcur], (float)run);
}

// ---------------- classifier ----------------
__global__ void k_classify(const float* __restrict__ pooled, const float* __restrict__ gcnt,
                           const float* __restrict__ Wc, const float* __restrict__ bc,
                           float* __restrict__ out) {
    int idx = blockIdx.x * blockDim.x + threadIdx.x;
    if (idx >= GG * CC) return;
    int g = idx >> 5, c = idx & 31;
    float inv = 1.f / fmaxf(gcnt[g], 1.f);
    float acc = bc[c];
    for (int k = 0; k < HH; k++) acc += pooled[g * HH + k] * inv * Wc[k * CC + c];
    out[idx] = acc;
}

extern "C" void kernel_launch(void* const* d_in, const int* in_sizes, int n_in,
                              void* d_out, int out_size, void* d_ws, size_t ws_size,
                              hipStream_t stream) {
    const float* x     = (const float*)d_in[0];
    const int*   ei    = (const int*)d_in[1];
    const int*   batch = (const int*)d_in[2];
    const float* W1 = (const float*)d_in[3];  const float* b1 = (const float*)d_in[4];
    const float* W2 = (const float*)d_in[5];  const float* b2 = (const float*)d_in[6];
    const float* W3 = (const float*)d_in[7];  const float* b3 = (const float*)d_in[8];
    const float* Wc = (const float*)d_in[9];  const float* bc = (const float*)d_in[10];
    float* out = (float*)d_out;

    const int* src = ei;
    const int* dst = ei + EE;

    char* w = (char*)d_ws;
    __half* h16     = (__half*)w;  w += (size_t)NN * HH * sizeof(__half);   // 25.6 MB
    __half* t16     = (__half*)w;  w += (size_t)NN * HH * sizeof(__half);   // 25.6 MB
    __half* x16     = (__half*)w;  w += (size_t)NN * HH * sizeof(__half);   // 25.6 MB
    __half* wt16    = (__half*)w;  w += (size_t)3 * HH * HH * sizeof(__half);
    float*  dinv    = (float*)w;   w += (size_t)NN * sizeof(float);
    int*    csr_src = (int*)w;     w += (size_t)ETOT * sizeof(int);         // 6.8 MB
    int*    row_off = (int*)w;     w += (size_t)(NN + 1) * sizeof(int);
    int*    counts  = (int*)w;     w += (size_t)NN * sizeof(int);
    int*    cursor  = (int*)w;     w += (size_t)NN * sizeof(int);
    int*    bsum    = (int*)w;     w += (size_t)SCAN_NB * sizeof(int);
    int*    boff    = (int*)w;     w += (size_t)SCAN_NB * sizeof(int);
    float*  pooled  = (float*)w;   w += (size_t)GG * HH * sizeof(float);
    float*  gcnt    = (float*)w;   w += (size_t)GG * sizeof(float);

    // prep + graph structure (rebuilt every call; deterministic work)
    k_init   <<<(NN + 255) / 256, 256, 0, stream>>>(counts, pooled, gcnt);
    k_x16    <<<(NN * HH / 4 + 255) / 256, 256, 0, stream>>>(x, x16);
    k_prepw  <<<3, 256, 0, stream>>>(W1, W2, W3, wt16);
    k_count  <<<(EE + 255) / 256, 256, 0, stream>>>(dst, counts);
    k_dinv   <<<(NN + 255) / 256, 256, 0, stream>>>(counts, dinv);
    k_psum   <<<SCAN_NB, SCAN_B, 0, stream>>>(counts, bsum);
    k_bscan  <<<1, 128, 0, stream>>>(bsum, boff);
    k_local  <<<SCAN_NB, SCAN_B, 0, stream>>>(counts, boff, row_off);
    k_self   <<<(NN + 255) / 256, 256, 0, stream>>>(row_off, cursor, csr_src);
    k_scatter<<<(EE + 255) / 256, 256, 0, stream>>>(src, dst, row_off, cursor, csr_src);

    const int gemm_grid = (NN + 127) / 128;   // 782
    const int agg_grid  = NN * 64 / 256;      // 25000 (one wave per node)

    // layer 1: x16 -> t16 (gemm*dinv) -> h16 (agg+bias+relu)
    k_gemm<<<gemm_grid, 256, 0, stream>>>(x16, wt16,               dinv, t16);
    k_agg <<<agg_grid, 256, 0, stream>>>(t16, h16, row_off, csr_src, dinv, b1, 1);
    // layer 2
    k_gemm<<<gemm_grid, 256, 0, stream>>>(h16, wt16 + HH * HH,     dinv, t16);
    k_agg <<<agg_grid, 256, 0, stream>>>(t16, h16, row_off, csr_src, dinv, b2, 1);
    // layer 3 (no relu)
    k_gemm<<<gemm_grid, 256, 0, stream>>>(h16, wt16 + 2 * HH * HH, dinv, t16);
    k_agg <<<agg_grid, 256, 0, stream>>>(t16, h16, row_off, csr_src, dinv, b3, 0);

    // pool + classify
    k_pool<<<(NN + 63) / 64, 128, 0, stream>>>(h16, batch, pooled, gcnt);
    k_classify<<<(GG * CC + 255) / 256, 256, 0, stream>>>(pooled, gcnt, Wc, bc, out);
}

// Round 6
// 354.377 us; speedup vs baseline: 2.8097x; 1.3251x over previous
//
#include <hip/hip_runtime.h>
#include <hip/hip_fp16.h>

#define NN 100000
#define EE 1600000
#define HH 128
#define GG 64
#define CC 32
#define ETOT (EE + NN)   // edges + self-loops

// bucketed-partition params
#define NB 256                      // dst buckets
#define BS 392                      // nodes per bucket (256*392 >= 100000)
#define CHUNK 8192                  // edges per partition block
#define NBLK ((EE + CHUNK - 1) / CHUNK)   // 196
#define MATL (NB * NBLK)            // 50176

typedef _Float16 half8 __attribute__((ext_vector_type(8)));
typedef float f32x4 __attribute__((ext_vector_type(4)));

// ---------------- init: zero pool accumulators ----------------
__global__ void k_init(float* __restrict__ pooled, float* __restrict__ gcnt) {
    int i = blockIdx.x * blockDim.x + threadIdx.x;
    if (i < GG * HH) pooled[i] = 0.f;
    if (i < GG) gcnt[i] = 0.f;
}

// ---------------- x -> fp16 ----------------
__global__ void k_x16(const float* __restrict__ x, __half* __restrict__ x16) {
    int i = blockIdx.x * blockDim.x + threadIdx.x;     // 4 floats per thread
    if (i >= NN * HH / 4) return;
    float4 v = ((const float4*)x)[i];
    ((__half2*)x16)[i * 2]     = __floats2half2_rn(v.x, v.y);
    ((__half2*)x16)[i * 2 + 1] = __floats2half2_rn(v.z, v.w);
}

// ---------------- W[k][n] fp32 -> Wt[n][k] fp16 (3 layers) ----------------
__global__ __launch_bounds__(256) void k_prepw(const float* __restrict__ W1, const float* __restrict__ W2,
                                               const float* __restrict__ W3, __half* __restrict__ wt) {
    __shared__ float sW[HH * (HH + 1)];
    const float* W = (blockIdx.x == 0) ? W1 : (blockIdx.x == 1) ? W2 : W3;
    __half* out = wt + (size_t)blockIdx.x * HH * HH;
    int t = threadIdx.x;
    #pragma unroll 4
    for (int i = 0; i < 64; i++) {
        int idx = i * 256 + t;
        sW[(idx >> 7) * (HH + 1) + (idx & 127)] = W[idx];
    }
    __syncthreads();
    #pragma unroll 4
    for (int i = 0; i < 64; i++) {
        int o = i * 256 + t;
        int n = o >> 7, k = o & 127;
        out[o] = __float2half(sW[k * (HH + 1) + n]);
    }
}

// ---------------- generalized 3-phase exclusive scan ----------------
__global__ __launch_bounds__(1024) void k_psumG(const int* __restrict__ in, int* __restrict__ bsum, int L) {
    __shared__ int red[1024];
    int i = blockIdx.x * 1024 + threadIdx.x;
    red[threadIdx.x] = (i < L) ? in[i] : 0;
    __syncthreads();
    for (int off = 512; off > 0; off >>= 1) {
        if (threadIdx.x < off) red[threadIdx.x] += red[threadIdx.x + off];
        __syncthreads();
    }
    if (threadIdx.x == 0) bsum[blockIdx.x] = red[0];
}
__global__ __launch_bounds__(1024) void k_bscanG(const int* __restrict__ bsum, int* __restrict__ boff, int nb) {
    __shared__ int s[1024];
    int t = threadIdx.x;
    s[t] = (t < nb) ? bsum[t] : 0;
    __syncthreads();
    for (int off = 1; off < 1024; off <<= 1) {
        int tmp = (t >= off) ? s[t - off] : 0;
        __syncthreads();
        s[t] += tmp;
        __syncthreads();
    }
    if (t < nb) boff[t] = s[t] - bsum[t];
}
__global__ __launch_bounds__(1024) void k_localG(const int* __restrict__ in, const int* __restrict__ boff,
                                                 int* __restrict__ off, int L, int total) {
    __shared__ int s[1024];
    int i = blockIdx.x * 1024 + threadIdx.x, t = threadIdx.x;
    int v = (i < L) ? in[i] : 0;
    s[t] = v;
    __syncthreads();
    for (int o = 1; o < 1024; o <<= 1) {
        int tmp = (t >= o) ? s[t - o] : 0;
        __syncthreads();
        s[t] += tmp;
        __syncthreads();
    }
    if (i < L) off[i] = boff[blockIdx.x] + s[t] - v;
    if (i == L - 1) off[L] = total;
}

// ---------------- phase A1: per-block bucket histogram -> mat[bucket][block] ----------------
__global__ __launch_bounds__(256) void k_hist(const int* __restrict__ dst, int* __restrict__ mat) {
    __shared__ int hist[NB];
    int t = threadIdx.x, blk = blockIdx.x;
    hist[t] = 0;                     // NB == 256 == blockDim
    __syncthreads();
    int base = blk * CHUNK;
    #pragma unroll 4
    for (int it = 0; it < CHUNK / 256; it++) {
        int e = base + it * 256 + t;
        if (e < EE) atomicAdd(&hist[dst[e] / BS], 1);
    }
    __syncthreads();
    mat[t * NBLK + blk] = hist[t];
}

// ---------------- phase A2: scatter edges into per-(block,bucket) runs ----------------
__global__ __launch_bounds__(256) void k_binscatter(const int* __restrict__ src, const int* __restrict__ dst,
                                                    const int* __restrict__ matscan, int* __restrict__ staged) {
    __shared__ int lcur[NB];
    int t = threadIdx.x, blk = blockIdx.x;
    lcur[t] = matscan[t * NBLK + blk];
    __syncthreads();
    int base = blk * CHUNK;
    #pragma unroll 4
    for (int it = 0; it < CHUNK / 256; it++) {
        int e = base + it * 256 + t;
        if (e < EE) {
            int d = dst[e], s = src[e];
            int b = d / BS;
            int pos = atomicAdd(&lcur[b], 1);
            staged[pos] = s | ((d - b * BS) << 17);     // src 17b | dst_local 9b
        }
    }
}

// ---------------- phase B1: per-bucket node degree counts (incl self) ----------------
__global__ __launch_bounds__(256) void k_bcount(const int* __restrict__ matscan, const int* __restrict__ staged,
                                                int* __restrict__ counts) {
    __shared__ int cnt[BS];
    int t = threadIdx.x, b = blockIdx.x;
    for (int i = t; i < BS; i += 256) cnt[i] = 1;       // self-loop
    __syncthreads();
    int beg = matscan[b * NBLK], end = matscan[(b + 1) * NBLK];
    for (int p = beg + t; p < end; p += 256) atomicAdd(&cnt[staged[p] >> 17], 1);
    __syncthreads();
    int nb0 = b * BS;
    for (int i = t; i < BS; i += 256) { int n = nb0 + i; if (n < NN) counts[n] = cnt[i]; }
}

// ---------------- dinv = rsqrt(counts) ----------------
__global__ void k_dinv(const int* __restrict__ counts, float* __restrict__ dinv) {
    int i = blockIdx.x * blockDim.x + threadIdx.x;
    if (i < NN) dinv[i] = rsqrtf((float)counts[i]);
}

// ---------------- phase B2: place edges into CSR (L2-local per bucket) ----------------
__global__ __launch_bounds__(256) void k_place(const int* __restrict__ matscan, const int* __restrict__ staged,
                                               const int* __restrict__ row_off, int* __restrict__ csr_src) {
    __shared__ int rof[BS];
    __shared__ int lcur[BS];
    int t = threadIdx.x, b = blockIdx.x;
    int nb0 = b * BS;
    for (int i = t; i < BS; i += 256) {
        int n = nb0 + i;
        int r = (n < NN) ? row_off[n] : 0;
        rof[i] = r; lcur[i] = 1;
        if (n < NN) csr_src[r] = n;                     // self edge in slot 0
    }
    __syncthreads();
    int beg = matscan[b * NBLK], end = matscan[(b + 1) * NBLK];
    for (int p = beg + t; p < end; p += 256) {
        int pk = staged[p];
        int dl = pk >> 17, s = pk & 0x1FFFF;
        int pos = rof[dl] + atomicAdd(&lcur[dl], 1);
        csr_src[pos] = s;
    }
}

// ---------------- MFMA GEMM: T[r][c](fp16) = dinv[r] * (A[r][:] @ W)[c] ----------------
__global__ __launch_bounds__(256) void k_gemm(const __half* __restrict__ A, const __half* __restrict__ Wt,
                                              const float* __restrict__ dinv, __half* __restrict__ T) {
    __shared__ __align__(16) char sm[64 * 1024];
    char* sA = sm;                 // 128 rows x 256B, XOR-swizzled
    char* sB = sm + 32 * 1024;
    int tid = threadIdx.x;
    int r0 = blockIdx.x * 128;

    const char* Ab = (const char*)A;
    #pragma unroll
    for (int it = 0; it < 8; it++) {
        int p = (tid + it * 256) * 16;
        int lrow = p >> 8;
        int grow = r0 + lrow; if (grow > NN - 1) grow = NN - 1;
        uint4 v = *(const uint4*)(Ab + (size_t)grow * 256 + (p & 255));
        *(uint4*)(sA + (p ^ ((lrow & 7) << 4))) = v;
    }
    const char* Wb = (const char*)Wt;
    #pragma unroll
    for (int it = 0; it < 8; it++) {
        int p = (tid + it * 256) * 16;
        int lrow = p >> 8;
        uint4 v = *(const uint4*)(Wb + p);
        *(uint4*)(sB + (p ^ ((lrow & 7) << 4))) = v;
    }
    __syncthreads();

    int w = tid >> 6;
    int lane = tid & 63;
    int q = lane >> 4;
    int ln = lane & 15;
    int wr = (w >> 1) * 64;
    int wc = (w & 1) * 64;

    f32x4 acc[4][4];
    #pragma unroll
    for (int a = 0; a < 4; a++)
        #pragma unroll
        for (int b = 0; b < 4; b++) acc[a][b] = (f32x4)0.f;

    #pragma unroll
    for (int ks = 0; ks < 4; ks++) {
        int koff = ks * 64 + q * 16;
        half8 af[4], bf[4];
        #pragma unroll
        for (int mi = 0; mi < 4; mi++) {
            int row = wr + mi * 16 + ln;
            af[mi] = *(half8*)(sA + row * 256 + (koff ^ ((row & 7) << 4)));
        }
        #pragma unroll
        for (int ni = 0; ni < 4; ni++) {
            int row = wc + ni * 16 + ln;
            bf[ni] = *(half8*)(sB + row * 256 + (koff ^ ((row & 7) << 4)));
        }
        #pragma unroll
        for (int mi = 0; mi < 4; mi++)
            #pragma unroll
            for (int ni = 0; ni < 4; ni++)
                acc[mi][ni] = __builtin_amdgcn_mfma_f32_16x16x32_f16(af[mi], bf[ni], acc[mi][ni], 0, 0, 0);
    }

    float dv[4][4];
    #pragma unroll
    for (int mi = 0; mi < 4; mi++)
        #pragma unroll
        for (int r = 0; r < 4; r++) {
            int grow = r0 + wr + mi * 16 + q * 4 + r;
            dv[mi][r] = dinv[grow < NN ? grow : 0];
        }
    #pragma unroll
    for (int mi = 0; mi < 4; mi++) {
        #pragma unroll
        for (int r = 0; r < 4; r++) {
            int grow = r0 + wr + mi * 16 + q * 4 + r;
            if (grow < NN) {
                #pragma unroll
                for (int ni = 0; ni < 4; ni++) {
                    int gcol = wc + ni * 16 + ln;
                    T[(size_t)grow * HH + gcol] = __float2half(acc[mi][ni][r] * dv[mi][r]);
                }
            }
        }
    }
}

// ---------------- aggregation: O[n] = relu?( dinv[n]*sum_{csr} T'[src] + bias ), fp16 in/out ----------------
__global__ __launch_bounds__(256) void k_agg(const __half* __restrict__ T, __half* __restrict__ O,
                                             const int* __restrict__ row_off, const int* __restrict__ csr_src,
                                             const float* __restrict__ dinv,
                                             const float* __restrict__ bias, int relu) {
    int gt = blockIdx.x * blockDim.x + threadIdx.x;
    int n = gt >> 6;
    if (n >= NN) return;
    int lane = threadIdx.x & 63;
    int g  = lane >> 4;
    int li = lane & 15;

    int beg = row_off[n], end = row_off[n + 1];
    int nit = (end - beg + 3) >> 2;

    float acc[8];
    #pragma unroll
    for (int c = 0; c < 8; c++) acc[c] = 0.f;

    int p = beg + g;
    #pragma unroll 2
    for (int i = 0; i < nit; i++, p += 4) {
        bool v = p < end;
        int s = csr_src[v ? p : beg];
        float m = v ? 1.f : 0.f;
        uint4 raw = *(const uint4*)(T + (size_t)s * HH + li * 8);
        const __half2* hp = (const __half2*)&raw;
        float2 f0 = __half22float2(hp[0]);
        float2 f1 = __half22float2(hp[1]);
        float2 f2 = __half22float2(hp[2]);
        float2 f3 = __half22float2(hp[3]);
        acc[0] += m * f0.x;  acc[1] += m * f0.y;
        acc[2] += m * f1.x;  acc[3] += m * f1.y;
        acc[4] += m * f2.x;  acc[5] += m * f2.y;
        acc[6] += m * f3.x;  acc[7] += m * f3.y;
    }

    #pragma unroll
    for (int c = 0; c < 8; c++) {
        acc[c] += __shfl_xor(acc[c], 16, 64);
        acc[c] += __shfl_xor(acc[c], 32, 64);
    }

    if (g == 0) {
        float dn = dinv[n];
        const float4* B4 = (const float4*)bias;
        float4 b0 = B4[li * 2], b1 = B4[li * 2 + 1];
        float o0 = dn * acc[0] + b0.x, o1 = dn * acc[1] + b0.y;
        float o2 = dn * acc[2] + b0.z, o3 = dn * acc[3] + b0.w;
        float o4 = dn * acc[4] + b1.x, o5 = dn * acc[5] + b1.y;
        float o6 = dn * acc[6] + b1.z, o7 = dn * acc[7] + b1.w;
        if (relu) {
            o0 = fmaxf(o0, 0.f); o1 = fmaxf(o1, 0.f); o2 = fmaxf(o2, 0.f); o3 = fmaxf(o3, 0.f);
            o4 = fmaxf(o4, 0.f); o5 = fmaxf(o5, 0.f); o6 = fmaxf(o6, 0.f); o7 = fmaxf(o7, 0.f);
        }
        union { uint4 u; __half2 h2[4]; } pk;
        pk.h2[0] = __floats2half2_rn(o0, o1);
        pk.h2[1] = __floats2half2_rn(o2, o3);
        pk.h2[2] = __floats2half2_rn(o4, o5);
        pk.h2[3] = __floats2half2_rn(o6, o7);
        *(uint4*)(O + (size_t)n * HH + li * 8) = pk.u;
    }
}

// ---------------- pooling: batch sorted -> run-length accumulate (fp16 in) ----------------
__global__ __launch_bounds__(128) void k_pool(const __half* __restrict__ Hm, const int* __restrict__ batch,
                                              float* __restrict__ pooled, float* __restrict__ gcnt) {
    int j = threadIdx.x;
    int n0 = blockIdx.x * 64;
    int nend = n0 + 64; if (nend > NN) nend = NN;
    float acc = 0.f;
    int gcur = batch[n0];
    int run = 0;
    for (int n = n0; n < nend; n++) {
        int g = batch[n];
        if (g != gcur) {
            atomicAdd(&pooled[gcur * HH + j], acc);
            if (j == 0) atomicAdd(&gcnt[gcur], (float)run);
            acc = 0.f; run = 0; gcur = g;
        }
        acc += __half2float(Hm[(size_t)n * HH + j]);
        run++;
    }
    atomicAdd(&pooled[gcur * HH + j], acc);
    if (j == 0) atomicAdd(&gcnt[gcur], (float)run);
}

// ---------------- classifier ----------------
__global__ void k_classify(const float* __restrict__ pooled, const float* __restrict__ gcnt,
                           const float* __restrict__ Wc, const float* __restrict__ bc,
                           float* __restrict__ out) {
    int idx = blockIdx.x * blockDim.x + threadIdx.x;
    if (idx >= GG * CC) return;
    int g = idx >> 5, c = idx & 31;
    float inv = 1.f / fmaxf(gcnt[g], 1.f);
    float acc = bc[c];
    for (int k = 0; k < HH; k++) acc += pooled[g * HH + k] * inv * Wc[k * CC + c];
    out[idx] = acc;
}

extern "C" void kernel_launch(void* const* d_in, const int* in_sizes, int n_in,
                              void* d_out, int out_size, void* d_ws, size_t ws_size,
                              hipStream_t stream) {
    const float* x     = (const float*)d_in[0];
    const int*   ei    = (const int*)d_in[1];
    const int*   batch = (const int*)d_in[2];
    const float* W1 = (const float*)d_in[3];  const float* b1 = (const float*)d_in[4];
    const float* W2 = (const float*)d_in[5];  const float* b2 = (const float*)d_in[6];
    const float* W3 = (const float*)d_in[7];  const float* b3 = (const float*)d_in[8];
    const float* Wc = (const float*)d_in[9];  const float* bc = (const float*)d_in[10];
    float* out = (float*)d_out;

    const int* src = ei;
    const int* dst = ei + EE;

    char* w = (char*)d_ws;
    __half* h16     = (__half*)w;  w += (size_t)NN * HH * sizeof(__half);   // 25.6 MB
    __half* t16     = (__half*)w;  w += (size_t)NN * HH * sizeof(__half);   // 25.6 MB
    __half* x16     = (__half*)w;  w += (size_t)NN * HH * sizeof(__half);   // 25.6 MB
    __half* wt16    = (__half*)w;  w += (size_t)3 * HH * HH * sizeof(__half);
    float*  dinv    = (float*)w;   w += (size_t)NN * sizeof(float);
    int*    csr_src = (int*)w;     w += (size_t)ETOT * sizeof(int);         // 6.8 MB
    int*    staged  = (int*)w;     w += (size_t)EE * sizeof(int);           // 6.4 MB
    int*    mat     = (int*)w;     w += (size_t)MATL * sizeof(int);
    int*    matscan = (int*)w;     w += (size_t)(MATL + 1) * sizeof(int);
    int*    row_off = (int*)w;     w += (size_t)(NN + 1) * sizeof(int);
    int*    counts  = (int*)w;     w += (size_t)NN * sizeof(int);
    int*    bsum    = (int*)w;     w += (size_t)1024 * sizeof(int);
    int*    boff    = (int*)w;     w += (size_t)1024 * sizeof(int);
    float*  pooled  = (float*)w;   w += (size_t)GG * HH * sizeof(float);
    float*  gcnt    = (float*)w;   w += (size_t)GG * sizeof(float);

    const int matblk = (MATL + 1023) / 1024;   // 49
    const int cntblk = (NN + 1023) / 1024;     // 98

    // prep
    k_init  <<<(GG * HH + 255) / 256, 256, 0, stream>>>(pooled, gcnt);
    k_x16   <<<(NN * HH / 4 + 255) / 256, 256, 0, stream>>>(x, x16);
    k_prepw <<<3, 256, 0, stream>>>(W1, W2, W3, wt16);

    // CSR build: bucketed two-phase partition
    k_hist      <<<NBLK, 256, 0, stream>>>(dst, mat);
    k_psumG     <<<matblk, 1024, 0, stream>>>(mat, bsum, MATL);
    k_bscanG    <<<1, 1024, 0, stream>>>(bsum, boff, matblk);
    k_localG    <<<matblk, 1024, 0, stream>>>(mat, boff, matscan, MATL, EE);
    k_binscatter<<<NBLK, 256, 0, stream>>>(src, dst, matscan, staged);
    k_bcount    <<<NB, 256, 0, stream>>>(matscan, staged, counts);
    k_dinv      <<<(NN + 255) / 256, 256, 0, stream>>>(counts, dinv);
    k_psumG     <<<cntblk, 1024, 0, stream>>>(counts, bsum, NN);
    k_bscanG    <<<1, 1024, 0, stream>>>(bsum, boff, cntblk);
    k_localG    <<<cntblk, 1024, 0, stream>>>(counts, boff, row_off, NN, ETOT);
    k_place     <<<NB, 256, 0, stream>>>(matscan, staged, row_off, csr_src);

    const int gemm_grid = (NN + 127) / 128;   // 782
    const int agg_grid  = NN * 64 / 256;      // 25000

    // layer 1
    k_gemm<<<gemm_grid, 256, 0, stream>>>(x16, wt16,               dinv, t16);
    k_agg <<<agg_grid, 256, 0, stream>>>(t16, h16, row_off, csr_src, dinv, b1, 1);
    // layer 2
    k_gemm<<<gemm_grid, 256, 0, stream>>>(h16, wt16 + HH * HH,     dinv, t16);
    k_agg <<<agg_grid, 256, 0, stream>>>(t16, h16, row_off, csr_src, dinv, b2, 1);
    // layer 3 (no relu)
    k_gemm<<<gemm_grid, 256, 0, stream>>>(h16, wt16 + 2 * HH * HH, dinv, t16);
    k_agg <<<agg_grid, 256, 0, stream>>>(t16, h16, row_off, csr_src, dinv, b3, 0);

    // pool + classify
    k_pool<<<(NN + 63) / 64, 128, 0, stream>>>(h16, batch, pooled, gcnt);
    k_classify<<<(GG * CC + 255) / 256, 256, 0, stream>>>(pooled, gcnt, Wc, bc, out);
}